// Round 1
// baseline (305.602 us; speedup 1.0000x reference)
//
#include <hip/hip_runtime.h>
#include <math.h>

// Problem constants (match reference)
#define NB 2
#define NS 8
#define NA 24000
#define NC 80
#define NM 20
#define NCE 7
#define NBS (NB*NS)          // 16 frames
#define CPB 75               // chunks (blocks) per frame
#define APC (NA/CPB)         // anchors per chunk = 320

#define POS_TH 0.5f
#define NEG_TH 0.4f
#define OMB 1e-4f            // 1.0 - 0.9999 (correctly rounded to f32)

// k_cls geometry: pure grid-stride stream over all logits
#define CLS_BLOCKS 2000
#define CLS_GSZ (CLS_BLOCKS*256)   // 512000 threads
#define CLS_PT 15                  // float4 per thread: 512000*15 = 7,680,000 = NBS*NA*NC/4

// pack (iou, anchor_idx) into u64 so that max-reduce picks higher iou,
// tie -> smaller anchor index (argmax first-occurrence semantics)
__device__ inline unsigned long long packKey(float f, unsigned idx) {
    unsigned u = __float_as_uint(f);
    u = (u & 0x80000000u) ? ~u : (u | 0x80000000u);   // total order on floats
    return ((unsigned long long)u << 32) | (unsigned long long)(0xFFFFFFFFu - idx);
}

// ---------------- kernel 1: IoU, per-anchor best gt, per-(gt,chunk) best anchor -------
__global__ void __launch_bounds__(256)
k_iou(const float* __restrict__ gtb, const int* __restrict__ counts,
      const float* __restrict__ anchors,
      float* __restrict__ bt_iou, int* __restrict__ bt_idx,
      unsigned long long* __restrict__ chunkbest) {
    int bid = blockIdx.x;
    int bs = bid / CPB;
    int chunk = bid % CPB;
    int t = threadIdx.x;
    int cnt = counts[bs];

    __shared__ float sg[NM][5];   // x1,y1,x2,y2,area (gt already point form)
    if (t < NM) {
        const float* g = gtb + ((size_t)bs * NM + t) * 4;
        float x1 = g[0], y1 = g[1], x2 = g[2], y2 = g[3];
        sg[t][0] = x1; sg[t][1] = y1; sg[t][2] = x2; sg[t][3] = y2;
        sg[t][4] = (x2 - x1) * (y2 - y1);
    }
    __syncthreads();

    unsigned long long bp[NM];
    #pragma unroll
    for (int m = 0; m < NM; m++) bp[m] = 0ULL;

    int a0 = chunk * APC;
    for (int a = a0 + t; a < a0 + APC; a += 256) {
        float4 cf = ((const float4*)anchors)[a];
        float ax1 = cf.x - cf.z * 0.5f, ay1 = cf.y - cf.w * 0.5f;
        float ax2 = cf.x + cf.z * 0.5f, ay2 = cf.y + cf.w * 0.5f;
        float aarea = (ax2 - ax1) * (ay2 - ay1);
        float best = -1.0f; int bm = 0;
        #pragma unroll
        for (int m = 0; m < NM; m++) {
            if (m < cnt) {
                float ltx = fmaxf(sg[m][0], ax1), lty = fmaxf(sg[m][1], ay1);
                float rbx = fminf(sg[m][2], ax2), rby = fminf(sg[m][3], ay2);
                float wx = fmaxf(rbx - ltx, 0.0f), wy = fmaxf(rby - lty, 0.0f);
                float inter = wx * wy;
                float iou = inter / (sg[m][4] + aarea - inter + 1e-10f);  // IEEE div: threshold-exact vs ref
                if (iou > best) { best = iou; bm = m; }   // strict >: first m wins ties
                unsigned long long k = packKey(iou, (unsigned)a);
                if (k > bp[m]) bp[m] = k;
            }
        }
        bt_iou[(size_t)bs * NA + a] = best;
        bt_idx[(size_t)bs * NA + a] = bm;
    }

    // per-wave shfl max, cross-wave via LDS, plain store to this block's chunk slots
    __shared__ unsigned long long sk[4][NM];
    int wave = t >> 6, lane = t & 63;
    for (int m = 0; m < cnt; m++) {       // cnt is block-uniform
        unsigned long long k = bp[m];
        #pragma unroll
        for (int off = 32; off > 0; off >>= 1) {
            unsigned long long o = __shfl_xor(k, off);
            if (o > k) k = o;
        }
        if (lane == 0) sk[wave][m] = k;
    }
    __syncthreads();
    if (t < NM) {
        unsigned long long k = 0ULL;
        if (t < cnt) {
            k = sk[0][t];
            if (sk[1][t] > k) k = sk[1][t];
            if (sk[2][t] > k) k = sk[2][t];
            if (sk[3][t] > k) k = sk[3][t];
        }
        chunkbest[bid * NM + t] = k;      // write all NM slots (ws is poisoned)
    }
}

// ---------------- kernel 2: one-block prep: CB weights, per-gt global best, acc init ---
// Hoists everything the old k_match recomputed redundantly in all 1200 blocks:
//  - wsn[80]: normalized class-balanced weights (powf chain, identical order -> bit-equal)
//  - gbest[bs][m]: argmax anchor over the CPB chunk slots (identical scan order)
//  - zeroes the accumulators
__global__ void k_prep(const int* __restrict__ cls_num,
                       const unsigned long long* __restrict__ chunkbest,
                       float* __restrict__ wsn, unsigned* __restrict__ gbest,
                       double* __restrict__ acc, int* __restrict__ npos) {
    __shared__ float wsh[NC];
    __shared__ float wsum_sh;
    int t = threadIdx.x;
    if (t == 0) { acc[0] = 0.0; acc[1] = 0.0; *npos = 0; }
    if (t < NC) {
        float n = (float)cls_num[t];
        wsh[t] = OMB / (1.0f - powf(0.9999f, n));
    }
    if (t < NBS * NM) {
        int bs = t / NM, m = t % NM;
        unsigned long long k = 0ULL;
        for (int c = 0; c < CPB; c++) {
            unsigned long long o = chunkbest[(bs * CPB + c) * NM + m];
            if (o > k) k = o;
        }
        gbest[t] = 0xFFFFFFFFu - (unsigned)(k & 0xFFFFFFFFull);  // garbage for m>=cnt, never read
    }
    __syncthreads();
    if (t == 0) {
        float s = 0.0f;
        for (int c = 0; c < NC; c++) s += wsh[c];
        wsum_sh = s;
    }
    __syncthreads();
    if (t < NC) wsn[t] = wsh[t] / wsum_sh;
}

// ---------------- kernel 3: match resolve + regression + pos-class correction ----------
// Phase-A only now. Writes the per-anchor cmask IN PLACE over bt_iou (same thread reads
// bt_iou[ia] before writing mask at ia; each index touched by exactly one thread).
__global__ void __launch_bounds__(256)
k_match(const float* __restrict__ gtb, const int* __restrict__ counts,
        const float* __restrict__ anchors, const float* __restrict__ ploc,
        const float* __restrict__ gtl, const float* __restrict__ logits,
        const float* __restrict__ wsn, const unsigned* __restrict__ gbest,
        float* bt_iou /* in: best-gt iou, out: cmask */, const int* __restrict__ bt_idx,
        double* __restrict__ acc, int* __restrict__ npos) {
    int bid = blockIdx.x;
    int bs = bid / CPB;
    int chunk = bid % CPB;
    int t = threadIdx.x;
    int cnt = counts[bs];

    __shared__ float sg[NM][4];
    __shared__ unsigned abest[NM];
    if (t < NM) {
        const float* g = gtb + ((size_t)bs * NM + t) * 4;
        sg[t][0] = g[0]; sg[t][1] = g[1]; sg[t][2] = g[2]; sg[t][3] = g[3];
        abest[t] = gbest[bs * NM + t];
    }
    __syncthreads();

    const float SL1B = 1.0f / 9.0f;
    float regsum = 0.0f, corrsum = 0.0f;
    int pcnt = 0;
    int a0 = chunk * APC;
    for (int al = t; al < APC; al += 256) {
        int a = a0 + al;
        size_t ia = (size_t)bs * NA + a;
        float iou = bt_iou[ia];
        int idx = bt_idx[ia];
        for (int m = 0; m < cnt; m++) {           // ascending: last match wins
            if (abest[m] == (unsigned)a) { iou = 2.0f; idx = m; }
        }
        int code;
        if (cnt == 0) code = -1;
        else if (iou < NEG_TH) code = 0;
        else if (iou < POS_TH) code = -1;
        else code = idx + 1;
        bt_iou[ia] = (code == -1) ? 0.0f : 1.0f;  // cmask for k_cls
        if (code > 0) {
            pcnt++;
            float4 cf = ((const float4*)anchors)[a];
            float mx1 = sg[idx][0], my1 = sg[idx][1], mx2 = sg[idx][2], my2 = sg[idx][3];
            float g0 = ((mx1 + mx2) * 0.5f - cf.x) / (0.1f * cf.z);
            float g1 = ((my1 + my2) * 0.5f - cf.y) / (0.1f * cf.w);
            float g2 = logf(fmaxf(mx2 - mx1, 1e-6f) / cf.z) / 0.2f;
            float g3 = logf(fmaxf(my2 - my1, 1e-6f) / cf.w) / 0.2f;
            float4 p = ((const float4*)ploc)[ia];
            float n0 = fabsf(p.x - g0), n1 = fabsf(p.y - g1);
            float n2 = fabsf(p.z - g2), n3 = fabsf(p.w - g3);
            float s0 = n0 < SL1B ? 0.5f * n0 * n0 / SL1B : n0 - 0.5f * SL1B;
            float s1 = n1 < SL1B ? 0.5f * n1 * n1 / SL1B : n1 - 0.5f * SL1B;
            float s2 = n2 < SL1B ? 0.5f * n2 * n2 / SL1B : n2 - 0.5f * SL1B;
            float s3 = n3 < SL1B ? 0.5f * n3 * n3 / SL1B : n3 - 0.5f * SL1B;
            regsum += s0 + s1 + s2 + s3;

            // pos-class correction over this anchor's y==1 classes (rare, ~4/80)
            const float4* yrow = (const float4*)(gtl + ((size_t)(bs * NM + idx)) * NC);
            const float4* xrow = (const float4*)(logits + ia * NC);
            #pragma unroll 4
            for (int c4 = 0; c4 < NC / 4; c4++) {
                float4 y4 = yrow[c4];
                if (y4.x > 0.5f || y4.y > 0.5f || y4.z > 0.5f || y4.w > 0.5f) {
                    float4 x4 = xrow[c4];
                    float yv[4] = {y4.x, y4.y, y4.z, y4.w};
                    float xv[4] = {x4.x, x4.y, x4.z, x4.w};
                    #pragma unroll
                    for (int j = 0; j < 4; j++) {
                        if (yv[j] > 0.5f) {
                            float x = xv[j];
                            float e = __expf(-x);
                            float s = 1.0f + e;
                            float pr = __builtin_amdgcn_rcpf(s);
                            float ls = __logf(s);
                            corrsum += ls * wsn[c4 * 4 + j] * (e * pr)
                                     - OMB * (x + ls) * pr;
                        }
                    }
                }
            }
        }
    }

    // wave shfl-reduce then cross-wave LDS then one atomic per block
    #pragma unroll
    for (int off = 32; off > 0; off >>= 1) {
        regsum  += __shfl_xor(regsum, off);
        corrsum += __shfl_xor(corrsum, off);
        pcnt    += __shfl_xor(pcnt, off);
    }
    __shared__ float sf[4], sc[4];
    __shared__ int   si[4];
    int wave = t >> 6, lane = t & 63;
    if (lane == 0) { sf[wave] = regsum; sc[wave] = corrsum; si[wave] = pcnt; }
    __syncthreads();
    if (t == 0) {
        atomicAdd(&acc[0], (double)(sf[0] + sf[1] + sf[2] + sf[3]));
        atomicAdd(&acc[1], (double)(sc[0] + sc[1] + sc[2] + sc[3]));
        atomicAdd(npos, si[0] + si[1] + si[2] + si[3]);
    }
}

// ---------------- kernel 4: background class-loss stream ------------------------------
// Pure grid-stride, no LDS, no barriers until the final reduce: mask-FMA of
// softplus(x)*sigmoid(x) over all 30.72M logits. Identities (e=exp(-x), s=1+e,
// p=1/s): -log(1-p) = x + log(s), contribution = (x+ls)*p per unmasked element.
// 2000 blocks * 4 waves = 7.8 waves/SIMD; batch-5 register staging keeps 5
// dwordx4 loads in flight per wave. Mask is 1.5MB -> L2-hit broadcast.
__global__ void __launch_bounds__(256, 8)
k_cls(const float* __restrict__ logits, const float* __restrict__ cmask,
      double* __restrict__ acc) {
    int gid = blockIdx.x * 256 + threadIdx.x;
    const float4* x4p = (const float4*)logits;
    float bgsum = 0.0f;
    #pragma unroll
    for (int g = 0; g < 3; g++) {
        float4 xs[5];
        float  ms[5];
        #pragma unroll
        for (int j = 0; j < 5; j++) {
            int i = gid + (g * 5 + j) * CLS_GSZ;
            ms[j] = cmask[i / 20];
            xs[j] = x4p[i];
        }
        #pragma unroll
        for (int j = 0; j < 5; j++) {
            float xv[4] = {xs[j].x, xs[j].y, xs[j].z, xs[j].w};
            float tsum = 0.0f;
            #pragma unroll
            for (int jj = 0; jj < 4; jj++) {
                float x = xv[jj];
                float e = __expf(-x);
                float s = 1.0f + e;
                float pr = __builtin_amdgcn_rcpf(s);
                float ls = __logf(s);
                tsum += (x + ls) * pr;
            }
            bgsum = fmaf(ms[j], tsum, bgsum);
        }
    }

    #pragma unroll
    for (int off = 32; off > 0; off >>= 1) bgsum += __shfl_xor(bgsum, off);
    __shared__ float sb[4];
    int t = threadIdx.x, wave = t >> 6, lane = t & 63;
    if (lane == 0) sb[wave] = bgsum;
    __syncthreads();
    if (t == 0) atomicAdd(&acc[1], (double)(OMB * (sb[0] + sb[1] + sb[2] + sb[3])));
}

// ---------------- kernel 5: ego focal loss + final combine ----------------
__global__ void k_final(const float* __restrict__ ego_preds, const int* __restrict__ ego_labels,
                        const double* __restrict__ acc, const int* __restrict__ npos,
                        float* __restrict__ out) {
    __shared__ float scol[NCE];
    __shared__ float sred[128];
    __shared__ int   sval[128];
    const float EPSF = 1e-7f;
    int t = threadIdx.x;
    if (t < NCE) {
        float c = 0.0f;
        for (int i = 0; i < NBS; i++) {
            int l = ego_labels[i];
            if (l > -1 && l == t) c = 1.0f;
        }
        scol[t] = c;
    }
    __syncthreads();

    float term = 0.0f;
    if (t < NBS * NCE) {
        int bs = t / NCE, e = t % NCE;
        int lbl = ego_labels[bs];
        if (lbl > -1) {
            float x = ego_preds[t];
            float ep = 1.0f / (1.0f + expf(-x));
            float oh = scol[e];
            float af = 0.25f * oh + 0.75f * (1.0f - oh);
            float ept = ep * oh + (1.0f - ep) * (1.0f - oh);
            float epc = fminf(fmaxf(ep, EPSF), 1.0f - EPSF);
            float bce = -(oh * logf(epc) + (1.0f - oh) * log1pf(-epc));
            float om = 1.0f - ept;
            term = bce * af * om * om;
        }
    }
    sred[t] = term;
    sval[t] = (t < NBS && ego_labels[t] > -1) ? 1 : 0;
    __syncthreads();
    for (int off = 64; off > 0; off >>= 1) {
        if (t < off) { sred[t] += sred[t + off]; sval[t] += sval[t + off]; }
        __syncthreads();
    }
    if (t == 0) {
        float esum = sred[0];
        int ne = sval[0];
        float ego = (ne > 0) ? esum / (float)(ne > 1 ? ne : 1) : 0.0f;
        double npd = (double)(*npos);
        if (npd < 1.0) npd = 1.0;
        out[0] = (float)(acc[0] / (npd * 4.0));
        out[1] = (float)(acc[1] / npd / 8.0 + (double)ego / 4.0);
    }
}

// ---------------- host launch ----------------
extern "C" void kernel_launch(void* const* d_in, const int* in_sizes, int n_in,
                              void* d_out, int out_size, void* d_ws, size_t ws_size,
                              hipStream_t stream) {
    const float* confidence = (const float*)d_in[0];
    const float* ploc       = (const float*)d_in[1];
    const float* gtb        = (const float*)d_in[2];
    const float* gtl        = (const float*)d_in[3];
    const int*   counts     = (const int*)d_in[4];
    const float* anchors    = (const float*)d_in[5];
    const float* ego_preds  = (const float*)d_in[6];
    const int*   ego_labels = (const int*)d_in[7];
    const int*   cls_num    = (const int*)d_in[8];
    float* out = (float*)d_out;

    // workspace layout (16B aligned chunks)
    char* ws = (char*)d_ws;
    double* acc  = (double*)ws;                               // [0]=reg_sum, [1]=cls_sum
    int* npos    = (int*)(ws + 16);
    unsigned long long* chunkbest = (unsigned long long*)(ws + 64);   // 1200*20 u64 = 192000 B
    float* bt_iou = (float*)(ws + 64 + 192000);               // 16*24000 f32 (later: cmask)
    int*   bt_idx = (int*)(ws + 64 + 192000 + 1536000);       // 16*24000 i32
    float* wsn    = (float*)(ws + 64 + 192000 + 1536000 + 1536000);        // 80 f32
    unsigned* gbest = (unsigned*)(ws + 64 + 192000 + 1536000 + 1536000 + 320); // 320 u32

    k_iou<<<NBS * CPB, 256, 0, stream>>>(gtb, counts, anchors, bt_iou, bt_idx, chunkbest);
    k_prep<<<1, 384, 0, stream>>>(cls_num, chunkbest, wsn, gbest, acc, npos);
    k_match<<<NBS * CPB, 256, 0, stream>>>(gtb, counts, anchors, ploc, gtl, confidence,
                                           wsn, gbest, bt_iou, bt_idx, acc, npos);
    k_cls<<<CLS_BLOCKS, 256, 0, stream>>>(confidence, bt_iou, acc);
    k_final<<<1, 128, 0, stream>>>(ego_preds, ego_labels, acc, npos, out);
}

// Round 2
// 305.321 us; speedup vs baseline: 1.0009x; 1.0009x over previous
//
#include <hip/hip_runtime.h>
#include <math.h>

// Problem constants (match reference)
#define NB 2
#define NS 8
#define NA 24000
#define NC 80
#define NM 20
#define NCE 7
#define NBS (NB*NS)          // 16 frames
#define CPB 75               // chunks (blocks) per frame
#define APC (NA/CPB)         // anchors per chunk = 320
#define F4PC (APC*NC/4)      // float4 per chunk = 6400 = 25*256 exactly

#define POS_TH 0.5f
#define NEG_TH 0.4f
#define OMB 1e-4f            // 1.0 - 0.9999 (correctly rounded to f32)

// pack (iou, anchor_idx) into u64 so that max-reduce picks higher iou,
// tie -> smaller anchor index (argmax first-occurrence semantics)
__device__ inline unsigned long long packKey(float f, unsigned idx) {
    unsigned u = __float_as_uint(f);
    u = (u & 0x80000000u) ? ~u : (u | 0x80000000u);   // total order on floats
    return ((unsigned long long)u << 32) | (unsigned long long)(0xFFFFFFFFu - idx);
}

// ---------------- kernel 1: IoU + best-gt/anchor + TOTAL background class sum ---------
// The background focal term OMB*(x+log s)*p summed over ALL logits is independent of
// the matching result, so it fuses here (each block owns a contiguous 100KB logits
// slab). k_match later subtracts the rows of ignored (code==-1) anchors.
__global__ void __launch_bounds__(256)
k_main(const float* __restrict__ gtb, const int* __restrict__ counts,
       const float* __restrict__ anchors, const float* __restrict__ logits,
       float* __restrict__ bt_iou, int* __restrict__ bt_idx,
       unsigned long long* __restrict__ chunkbest,
       double* __restrict__ bgpart) {
    int bid = blockIdx.x;
    int bs = bid / CPB;
    int chunk = bid % CPB;
    int t = threadIdx.x;
    int cnt = counts[bs];

    __shared__ float sg[NM][5];   // x1,y1,x2,y2,area (gt already point form)
    if (t < NM) {
        const float* g = gtb + ((size_t)bs * NM + t) * 4;
        float x1 = g[0], y1 = g[1], x2 = g[2], y2 = g[3];
        sg[t][0] = x1; sg[t][1] = y1; sg[t][2] = x2; sg[t][3] = y2;
        sg[t][4] = (x2 - x1) * (y2 - y1);
    }
    __syncthreads();

    unsigned long long bp[NM];
    #pragma unroll
    for (int m = 0; m < NM; m++) bp[m] = 0ULL;

    int a0 = chunk * APC;
    for (int a = a0 + t; a < a0 + APC; a += 256) {
        float4 cf = ((const float4*)anchors)[a];
        float ax1 = cf.x - cf.z * 0.5f, ay1 = cf.y - cf.w * 0.5f;
        float ax2 = cf.x + cf.z * 0.5f, ay2 = cf.y + cf.w * 0.5f;
        float aarea = (ax2 - ax1) * (ay2 - ay1);
        float best = -1.0f; int bm = 0;
        #pragma unroll
        for (int m = 0; m < NM; m++) {
            if (m < cnt) {
                float ltx = fmaxf(sg[m][0], ax1), lty = fmaxf(sg[m][1], ay1);
                float rbx = fminf(sg[m][2], ax2), rby = fminf(sg[m][3], ay2);
                float wx = fmaxf(rbx - ltx, 0.0f), wy = fmaxf(rby - lty, 0.0f);
                float inter = wx * wy;
                float iou = inter / (sg[m][4] + aarea - inter + 1e-10f);  // IEEE div: threshold-exact vs ref
                if (iou > best) { best = iou; bm = m; }   // strict >: first m wins ties
                unsigned long long k = packKey(iou, (unsigned)a);
                if (k > bp[m]) bp[m] = k;
            }
        }
        bt_iou[(size_t)bs * NA + a] = best;
        bt_idx[(size_t)bs * NA + a] = bm;
    }

    // per-wave shfl max, cross-wave via LDS, plain store to this block's chunk slots
    __shared__ unsigned long long sk[4][NM];
    int wave = t >> 6, lane = t & 63;
    for (int m = 0; m < cnt; m++) {       // cnt is block-uniform
        unsigned long long k = bp[m];
        #pragma unroll
        for (int off = 32; off > 0; off >>= 1) {
            unsigned long long o = __shfl_xor(k, off);
            if (o > k) k = o;
        }
        if (lane == 0) sk[wave][m] = k;
    }
    __syncthreads();
    if (t < NM) {
        unsigned long long k = 0ULL;
        if (t < cnt) {
            k = sk[0][t];
            if (sk[1][t] > k) k = sk[1][t];
            if (sk[2][t] > k) k = sk[2][t];
            if (sk[3][t] > k) k = sk[3][t];
        }
        chunkbest[bid * NM + t] = k;      // write all NM slots (ws is poisoned)
    }

    // ---- total background sum over this block's contiguous logits slab --------------
    // Identities (e=exp(-x), s=1+e, p=1/s): -log(1-p) = x + log(s); term = (x+ls)*p.
    // batch-5 register staging, 25 float4/thread, accumulate in double.
    const float4* x4p = (const float4*)logits + ((size_t)bs * NA + a0) * (NC / 4);
    double bg = 0.0;
    #pragma unroll
    for (int g = 0; g < 5; g++) {
        float4 xs[5];
        #pragma unroll
        for (int j = 0; j < 5; j++) xs[j] = x4p[t + (g * 5 + j) * 256];
        #pragma unroll
        for (int j = 0; j < 5; j++) {
            float xv[4] = {xs[j].x, xs[j].y, xs[j].z, xs[j].w};
            float tsum = 0.0f;
            #pragma unroll
            for (int jj = 0; jj < 4; jj++) {
                float x = xv[jj];
                float e = __expf(-x);
                float s = 1.0f + e;
                float pr = __builtin_amdgcn_rcpf(s);
                float ls = __logf(s);
                tsum += (x + ls) * pr;
            }
            bg += (double)tsum;
        }
    }
    #pragma unroll
    for (int off = 32; off > 0; off >>= 1) bg += __shfl_xor(bg, off);
    __shared__ double sb[4];
    if (lane == 0) sb[wave] = bg;
    __syncthreads();
    if (t == 0) bgpart[bid] = sb[0] + sb[1] + sb[2] + sb[3];
}

// ---------------- kernel 2: one-block prep -------------------------------------------
//  - wsn[80]: normalized class-balanced weights (identical op order -> bit-equal)
//  - gbest[bs][m]: argmax anchor over the CPB chunk slots (identical scan order)
//  - acc[1] initialized to OMB * total_bg (from bgpart); acc[0]/npos zeroed
__global__ void k_prep(const int* __restrict__ cls_num,
                       const unsigned long long* __restrict__ chunkbest,
                       const double* __restrict__ bgpart,
                       float* __restrict__ wsn, unsigned* __restrict__ gbest,
                       double* __restrict__ acc, int* __restrict__ npos) {
    __shared__ float wsh[NC];
    __shared__ float wsum_sh;
    __shared__ double sred[6];
    int t = threadIdx.x;
    if (t == 0) { acc[0] = 0.0; *npos = 0; }
    if (t < NC) {
        float n = (float)cls_num[t];
        wsh[t] = OMB / (1.0f - powf(0.9999f, n));
    }
    if (t < NBS * NM) {
        int bs = t / NM, m = t % NM;
        unsigned long long k = 0ULL;
        for (int c = 0; c < CPB; c++) {
            unsigned long long o = chunkbest[(bs * CPB + c) * NM + m];
            if (o > k) k = o;
        }
        gbest[t] = 0xFFFFFFFFu - (unsigned)(k & 0xFFFFFFFFull);  // garbage for m>=cnt, never read
    }
    // total background
    double b = 0.0;
    for (int i = t; i < NBS * CPB; i += 384) b += bgpart[i];
    #pragma unroll
    for (int off = 32; off > 0; off >>= 1) b += __shfl_xor(b, off);
    int wave = t >> 6, lane = t & 63;
    if (lane == 0) sred[wave] = b;
    __syncthreads();
    if (t == 0) {
        double s = 0.0;
        for (int w = 0; w < 6; w++) s += sred[w];
        acc[1] = (double)OMB * s;
        float ws = 0.0f;
        for (int c = 0; c < NC; c++) ws += wsh[c];
        wsum_sh = ws;
    }
    __syncthreads();
    if (t < NC) wsn[t] = wsh[t] / wsum_sh;
}

// ---------------- kernel 3: match resolve + regression + class corrections ------------
// Positive anchors: regression loss + per-class (y==1) replacement of the background
// formula by the weighted positive formula. Ignored anchors (code==-1, incl. empty
// frames): subtract their whole 80-class background row from the total.
__global__ void __launch_bounds__(256)
k_match(const float* __restrict__ gtb, const int* __restrict__ counts,
        const float* __restrict__ anchors, const float* __restrict__ ploc,
        const float* __restrict__ gtl, const float* __restrict__ logits,
        const float* __restrict__ wsn, const unsigned* __restrict__ gbest,
        const float* __restrict__ bt_iou, const int* __restrict__ bt_idx,
        double* __restrict__ acc, int* __restrict__ npos) {
    int bid = blockIdx.x;
    int bs = bid / CPB;
    int chunk = bid % CPB;
    int t = threadIdx.x;
    int cnt = counts[bs];

    __shared__ float sg[NM][4];
    __shared__ unsigned abest[NM];
    if (t < NM) {
        const float* g = gtb + ((size_t)bs * NM + t) * 4;
        sg[t][0] = g[0]; sg[t][1] = g[1]; sg[t][2] = g[2]; sg[t][3] = g[3];
        abest[t] = gbest[bs * NM + t];
    }
    __syncthreads();

    const float SL1B = 1.0f / 9.0f;
    float regsum = 0.0f, corrsum = 0.0f, negsum = 0.0f;
    int pcnt = 0;
    int a0 = chunk * APC;
    for (int al = t; al < APC; al += 256) {
        int a = a0 + al;
        size_t ia = (size_t)bs * NA + a;
        float iou = bt_iou[ia];
        int idx = bt_idx[ia];
        for (int m = 0; m < cnt; m++) {           // ascending: last match wins
            if (abest[m] == (unsigned)a) { iou = 2.0f; idx = m; }
        }
        int code;
        if (cnt == 0) code = -1;
        else if (iou < NEG_TH) code = 0;
        else if (iou < POS_TH) code = -1;
        else code = idx + 1;
        if (code > 0) {
            pcnt++;
            float4 cf = ((const float4*)anchors)[a];
            float mx1 = sg[idx][0], my1 = sg[idx][1], mx2 = sg[idx][2], my2 = sg[idx][3];
            float g0 = ((mx1 + mx2) * 0.5f - cf.x) / (0.1f * cf.z);
            float g1 = ((my1 + my2) * 0.5f - cf.y) / (0.1f * cf.w);
            float g2 = logf(fmaxf(mx2 - mx1, 1e-6f) / cf.z) / 0.2f;
            float g3 = logf(fmaxf(my2 - my1, 1e-6f) / cf.w) / 0.2f;
            float4 p = ((const float4*)ploc)[ia];
            float n0 = fabsf(p.x - g0), n1 = fabsf(p.y - g1);
            float n2 = fabsf(p.z - g2), n3 = fabsf(p.w - g3);
            float s0 = n0 < SL1B ? 0.5f * n0 * n0 / SL1B : n0 - 0.5f * SL1B;
            float s1 = n1 < SL1B ? 0.5f * n1 * n1 / SL1B : n1 - 0.5f * SL1B;
            float s2 = n2 < SL1B ? 0.5f * n2 * n2 / SL1B : n2 - 0.5f * SL1B;
            float s3 = n3 < SL1B ? 0.5f * n3 * n3 / SL1B : n3 - 0.5f * SL1B;
            regsum += s0 + s1 + s2 + s3;

            // pos-class correction over this anchor's y==1 classes (rare, ~4/80)
            const float4* yrow = (const float4*)(gtl + ((size_t)(bs * NM + idx)) * NC);
            const float4* xrow = (const float4*)(logits + ia * NC);
            #pragma unroll 4
            for (int c4 = 0; c4 < NC / 4; c4++) {
                float4 y4 = yrow[c4];
                if (y4.x > 0.5f || y4.y > 0.5f || y4.z > 0.5f || y4.w > 0.5f) {
                    float4 x4 = xrow[c4];
                    float yv[4] = {y4.x, y4.y, y4.z, y4.w};
                    float xv[4] = {x4.x, x4.y, x4.z, x4.w};
                    #pragma unroll
                    for (int j = 0; j < 4; j++) {
                        if (yv[j] > 0.5f) {
                            float x = xv[j];
                            float e = __expf(-x);
                            float s = 1.0f + e;
                            float pr = __builtin_amdgcn_rcpf(s);
                            float ls = __logf(s);
                            corrsum += ls * wsn[c4 * 4 + j] * (e * pr)
                                     - OMB * (x + ls) * pr;
                        }
                    }
                }
            }
        } else if (code == -1) {
            // ignored anchor: remove its whole background row from the total
            const float4* xrow = (const float4*)(logits + ia * NC);
            float rs = 0.0f;
            #pragma unroll 5
            for (int c4 = 0; c4 < NC / 4; c4++) {
                float4 x4 = xrow[c4];
                float xv[4] = {x4.x, x4.y, x4.z, x4.w};
                #pragma unroll
                for (int j = 0; j < 4; j++) {
                    float x = xv[j];
                    float e = __expf(-x);
                    float s = 1.0f + e;
                    float pr = __builtin_amdgcn_rcpf(s);
                    float ls = __logf(s);
                    rs += (x + ls) * pr;
                }
            }
            negsum += rs;
        }
    }

    float clssum = corrsum - OMB * negsum;
    // wave shfl-reduce then cross-wave LDS then one atomic per block
    #pragma unroll
    for (int off = 32; off > 0; off >>= 1) {
        regsum += __shfl_xor(regsum, off);
        clssum += __shfl_xor(clssum, off);
        pcnt   += __shfl_xor(pcnt, off);
    }
    __shared__ float sf[4], sc[4];
    __shared__ int   si[4];
    int wave = t >> 6, lane = t & 63;
    if (lane == 0) { sf[wave] = regsum; sc[wave] = clssum; si[wave] = pcnt; }
    __syncthreads();
    if (t == 0) {
        atomicAdd(&acc[0], (double)(sf[0] + sf[1] + sf[2] + sf[3]));
        atomicAdd(&acc[1], (double)(sc[0] + sc[1] + sc[2] + sc[3]));
        atomicAdd(npos, si[0] + si[1] + si[2] + si[3]);
    }
}

// ---------------- kernel 4: ego focal loss + final combine ----------------
__global__ void k_final(const float* __restrict__ ego_preds, const int* __restrict__ ego_labels,
                        const double* __restrict__ acc, const int* __restrict__ npos,
                        float* __restrict__ out) {
    __shared__ float scol[NCE];
    __shared__ float sred[128];
    __shared__ int   sval[128];
    const float EPSF = 1e-7f;
    int t = threadIdx.x;
    if (t < NCE) {
        float c = 0.0f;
        for (int i = 0; i < NBS; i++) {
            int l = ego_labels[i];
            if (l > -1 && l == t) c = 1.0f;
        }
        scol[t] = c;
    }
    __syncthreads();

    float term = 0.0f;
    if (t < NBS * NCE) {
        int bs = t / NCE, e = t % NCE;
        int lbl = ego_labels[bs];
        if (lbl > -1) {
            float x = ego_preds[t];
            float ep = 1.0f / (1.0f + expf(-x));
            float oh = scol[e];
            float af = 0.25f * oh + 0.75f * (1.0f - oh);
            float ept = ep * oh + (1.0f - ep) * (1.0f - oh);
            float epc = fminf(fmaxf(ep, EPSF), 1.0f - EPSF);
            float bce = -(oh * logf(epc) + (1.0f - oh) * log1pf(-epc));
            float om = 1.0f - ept;
            term = bce * af * om * om;
        }
    }
    sred[t] = term;
    sval[t] = (t < NBS && ego_labels[t] > -1) ? 1 : 0;
    __syncthreads();
    for (int off = 64; off > 0; off >>= 1) {
        if (t < off) { sred[t] += sred[t + off]; sval[t] += sval[t + off]; }
        __syncthreads();
    }
    if (t == 0) {
        float esum = sred[0];
        int ne = sval[0];
        float ego = (ne > 0) ? esum / (float)(ne > 1 ? ne : 1) : 0.0f;
        double npd = (double)(*npos);
        if (npd < 1.0) npd = 1.0;
        out[0] = (float)(acc[0] / (npd * 4.0));
        out[1] = (float)(acc[1] / npd / 8.0 + (double)ego / 4.0);
    }
}

// ---------------- host launch ----------------
extern "C" void kernel_launch(void* const* d_in, const int* in_sizes, int n_in,
                              void* d_out, int out_size, void* d_ws, size_t ws_size,
                              hipStream_t stream) {
    const float* confidence = (const float*)d_in[0];
    const float* ploc       = (const float*)d_in[1];
    const float* gtb        = (const float*)d_in[2];
    const float* gtl        = (const float*)d_in[3];
    const int*   counts     = (const int*)d_in[4];
    const float* anchors    = (const float*)d_in[5];
    const float* ego_preds  = (const float*)d_in[6];
    const int*   ego_labels = (const int*)d_in[7];
    const int*   cls_num    = (const int*)d_in[8];
    float* out = (float*)d_out;

    // workspace layout (16B aligned chunks)
    char* ws = (char*)d_ws;
    double* acc  = (double*)ws;                               // [0]=reg_sum, [1]=cls_sum
    int* npos    = (int*)(ws + 16);
    unsigned long long* chunkbest = (unsigned long long*)(ws + 64);     // 1200*20 u64 = 192000 B
    float* bt_iou = (float*)(ws + 64 + 192000);               // 16*24000 f32
    int*   bt_idx = (int*)(ws + 64 + 192000 + 1536000);       // 16*24000 i32
    float* wsn    = (float*)(ws + 64 + 192000 + 1536000 + 1536000);          // 80 f32
    unsigned* gbest = (unsigned*)(ws + 64 + 192000 + 1536000 + 1536000 + 320);   // 320 u32
    double* bgpart  = (double*)(ws + 64 + 192000 + 1536000 + 1536000 + 320 + 1280); // 1200 f64

    k_main<<<NBS * CPB, 256, 0, stream>>>(gtb, counts, anchors, confidence,
                                          bt_iou, bt_idx, chunkbest, bgpart);
    k_prep<<<1, 384, 0, stream>>>(cls_num, chunkbest, bgpart, wsn, gbest, acc, npos);
    k_match<<<NBS * CPB, 256, 0, stream>>>(gtb, counts, anchors, ploc, gtl, confidence,
                                           wsn, gbest, bt_iou, bt_idx, acc, npos);
    k_final<<<1, 128, 0, stream>>>(ego_preds, ego_labels, acc, npos, out);
}

// Round 3
// 275.556 us; speedup vs baseline: 1.1090x; 1.1080x over previous
//
#include <hip/hip_runtime.h>
#include <math.h>

// Problem constants (match reference)
#define NB 2
#define NS 8
#define NA 24000
#define NC 80
#define NM 20
#define NCE 7
#define NBS (NB*NS)          // 16 frames
#define CPB 75               // chunks (blocks) per frame
#define APC (NA/CPB)         // anchors per chunk = 320

#define POS_TH 0.5f
#define NEG_TH 0.4f
#define OMB 1e-4f            // 1.0 - 0.9999 (correctly rounded to f32)

// pack (iou, anchor_idx) into u64 so that max-reduce picks higher iou,
// tie -> smaller anchor index (argmax first-occurrence semantics)
__device__ inline unsigned long long packKey(float f, unsigned idx) {
    unsigned u = __float_as_uint(f);
    u = (u & 0x80000000u) ? ~u : (u | 0x80000000u);   // total order on floats
    return ((unsigned long long)u << 32) | (unsigned long long)(0xFFFFFFFFu - idx);
}

// non-temporal float4 load: no L2/L3 allocation -> no dirty-victim writebacks
// (the poison fill leaves caches full of dirty lines; counters showed
//  WRITE_SIZE ~= FETCH_SIZE on read-only streams)
typedef float v4f __attribute__((ext_vector_type(4)));
__device__ inline float4 ntload4(const float4* p) {
    v4f v = __builtin_nontemporal_load((const v4f*)p);
    return make_float4(v.x, v.y, v.z, v.w);
}

// ---------------- kernel 1: per-gt global best anchor via atomicMax ----------------
// Only cross-chunk-global quantity in the whole problem: argmax_a IoU(gt m, a).
// Per chunk: per-gt wave/LDS max of packKey, then one u64 atomicMax per gt.
__global__ void __launch_bounds__(256)
k_gbest(const float* __restrict__ gtb, const int* __restrict__ counts,
        const float* __restrict__ anchors, unsigned long long* __restrict__ gbest) {
    int bid = blockIdx.x;
    int bs = bid / CPB;
    int chunk = bid % CPB;
    int t = threadIdx.x;
    int cnt = counts[bs];
    if (cnt == 0) return;                 // block-uniform: all threads exit together

    __shared__ float sg[NM][5];           // x1,y1,x2,y2,area (gt already point form)
    if (t < NM) {
        const float* g = gtb + ((size_t)bs * NM + t) * 4;
        float x1 = g[0], y1 = g[1], x2 = g[2], y2 = g[3];
        sg[t][0] = x1; sg[t][1] = y1; sg[t][2] = x2; sg[t][3] = y2;
        sg[t][4] = (x2 - x1) * (y2 - y1);
    }
    __syncthreads();

    int a0 = chunk * APC;
    // anchor 1: a0+t (all threads); anchor 2: a0+256+t (threads 0..63)
    bool has2 = t < (APC - 256);
    float4 c1 = ((const float4*)anchors)[a0 + t];
    float bx1 = c1.x - c1.z * 0.5f, by1 = c1.y - c1.w * 0.5f;
    float bx2 = c1.x + c1.z * 0.5f, by2 = c1.y + c1.w * 0.5f;
    float bar = (bx2 - bx1) * (by2 - by1);
    float cx1 = 0, cy1 = 0, cx2 = 0, cy2 = 0, car = 0;
    if (has2) {
        float4 c2 = ((const float4*)anchors)[a0 + 256 + t];
        cx1 = c2.x - c2.z * 0.5f; cy1 = c2.y - c2.w * 0.5f;
        cx2 = c2.x + c2.z * 0.5f; cy2 = c2.y + c2.w * 0.5f;
        car = (cx2 - cx1) * (cy2 - cy1);
    }

    __shared__ unsigned long long sk[4][NM];
    int wave = t >> 6, lane = t & 63;
    for (int m = 0; m < cnt; m++) {
        float gx1 = sg[m][0], gy1 = sg[m][1], gx2 = sg[m][2], gy2 = sg[m][3], gar = sg[m][4];
        // anchor 1
        float ltx = fmaxf(gx1, bx1), lty = fmaxf(gy1, by1);
        float rbx = fminf(gx2, bx2), rby = fminf(gy2, by2);
        float wx = fmaxf(rbx - ltx, 0.0f), wy = fmaxf(rby - lty, 0.0f);
        float inter = wx * wy;
        float iou = inter / (gar + bar - inter + 1e-10f);   // IEEE div: threshold-exact vs ref
        unsigned long long k = packKey(iou, (unsigned)(a0 + t));
        if (has2) {
            float ltx2 = fmaxf(gx1, cx1), lty2 = fmaxf(gy1, cy1);
            float rbx2 = fminf(gx2, cx2), rby2 = fminf(gy2, cy2);
            float wx2 = fmaxf(rbx2 - ltx2, 0.0f), wy2 = fmaxf(rby2 - lty2, 0.0f);
            float inter2 = wx2 * wy2;
            float iou2 = inter2 / (gar + car - inter2 + 1e-10f);
            unsigned long long k2 = packKey(iou2, (unsigned)(a0 + 256 + t));
            if (k2 > k) k = k2;
        }
        #pragma unroll
        for (int off = 32; off > 0; off >>= 1) {
            unsigned long long o = __shfl_xor(k, off);
            if (o > k) k = o;
        }
        if (lane == 0) sk[wave][m] = k;
    }
    __syncthreads();
    if (t < cnt) {
        unsigned long long k = sk[0][t];
        if (sk[1][t] > k) k = sk[1][t];
        if (sk[2][t] > k) k = sk[2][t];
        if (sk[3][t] > k) k = sk[3][t];
        atomicMax(&gbest[bs * NM + t], k);
    }
}

// ---------------- kernel 2: fused match + regression + class loss (ONE logits pass) ---
// Phase A (per anchor): recompute best-gt IoU (cheap VALU), resolve force-match from
// gbest, codes, mask -> LDS, regression loss, compact positives into an LDS queue.
// Phase B: dense branch-free mask-FMA over this block's CONTIGUOUS logits slab with
// NT loads (batch-5 register staging), then cooperative (divergence-free, coalesced)
// processing of the positive queue for the y==1 class corrections.
// Identities (e=exp(-x), s=1+e, p=1/s): -log(p)=log(s), -log(1-p)=x+log(s), 1-p=e*p.
__global__ void __launch_bounds__(256, 5)
k_match(const float* __restrict__ gtb, const int* __restrict__ counts,
        const float* __restrict__ anchors, const float* __restrict__ ploc,
        const float* __restrict__ gtl, const float* __restrict__ logits,
        const int* __restrict__ cls_num,
        const unsigned long long* __restrict__ gbest,
        double* __restrict__ acc, int* __restrict__ npos) {
    int bid = blockIdx.x;
    int bs = bid / CPB;
    int chunk = bid % CPB;
    int t = threadIdx.x;
    int cnt = counts[bs];

    __shared__ float sg[NM][5];
    __shared__ unsigned abest[NM];
    __shared__ float wsh[NC];
    __shared__ float wsum_sh;
    __shared__ float smask[APC];     // per-anchor cmask (0 = ignore, 1 = contributes)
    __shared__ unsigned qpos[APC];   // compacted positives: (gt_idx<<16) | local_anchor
    __shared__ int npq;
    if (t == 0) npq = 0;
    if (t < NM) {
        const float* g = gtb + ((size_t)bs * NM + t) * 4;
        float x1 = g[0], y1 = g[1], x2 = g[2], y2 = g[3];
        sg[t][0] = x1; sg[t][1] = y1; sg[t][2] = x2; sg[t][3] = y2;
        sg[t][4] = (x2 - x1) * (y2 - y1);
        if (t < cnt)
            abest[t] = 0xFFFFFFFFu - (unsigned)(gbest[bs * NM + t] & 0xFFFFFFFFull);
    }
    // CB weights, computed redundantly per block (80 powf — negligible)
    if (t < NC) {
        float n = (float)cls_num[t];
        wsh[t] = OMB / (1.0f - powf(0.9999f, n));   // numerator cancels in normalization
    }
    __syncthreads();
    if (t == 0) {
        float s = 0.0f;
        for (int c = 0; c < NC; c++) s += wsh[c];
        wsum_sh = s;
    }
    __syncthreads();
    if (t < NC) wsh[t] = wsh[t] / wsum_sh;   // safe: wsh not read until after next barrier

    // ---------------- phase A: codes + regression + positive queue ----------------
    const float SL1B = 1.0f / 9.0f;
    float regsum = 0.0f;
    int pcnt = 0;
    int a0 = chunk * APC;
    for (int al = t; al < APC; al += 256) {
        int a = a0 + al;
        float4 cf = ((const float4*)anchors)[a];
        float ax1 = cf.x - cf.z * 0.5f, ay1 = cf.y - cf.w * 0.5f;
        float ax2 = cf.x + cf.z * 0.5f, ay2 = cf.y + cf.w * 0.5f;
        float aarea = (ax2 - ax1) * (ay2 - ay1);
        float best = -1.0f; int bm = 0;
        for (int m = 0; m < cnt; m++) {
            float ltx = fmaxf(sg[m][0], ax1), lty = fmaxf(sg[m][1], ay1);
            float rbx = fminf(sg[m][2], ax2), rby = fminf(sg[m][3], ay2);
            float wx = fmaxf(rbx - ltx, 0.0f), wy = fmaxf(rby - lty, 0.0f);
            float inter = wx * wy;
            float iou = inter / (sg[m][4] + aarea - inter + 1e-10f);
            if (iou > best) { best = iou; bm = m; }   // strict >: first m wins ties
        }
        for (int m = 0; m < cnt; m++) {               // ascending: last match wins
            if (abest[m] == (unsigned)a) { best = 2.0f; bm = m; }
        }
        int code;
        if (cnt == 0) code = -1;
        else if (best < NEG_TH) code = 0;
        else if (best < POS_TH) code = -1;
        else code = bm + 1;
        smask[al] = (code == -1) ? 0.0f : 1.0f;
        if (code > 0) {
            pcnt++;
            size_t ia = (size_t)bs * NA + a;
            float mx1 = sg[bm][0], my1 = sg[bm][1], mx2 = sg[bm][2], my2 = sg[bm][3];
            float g0 = ((mx1 + mx2) * 0.5f - cf.x) / (0.1f * cf.z);
            float g1 = ((my1 + my2) * 0.5f - cf.y) / (0.1f * cf.w);
            float g2 = logf(fmaxf(mx2 - mx1, 1e-6f) / cf.z) / 0.2f;
            float g3 = logf(fmaxf(my2 - my1, 1e-6f) / cf.w) / 0.2f;
            float4 p = ((const float4*)ploc)[ia];
            float n0 = fabsf(p.x - g0), n1 = fabsf(p.y - g1);
            float n2 = fabsf(p.z - g2), n3 = fabsf(p.w - g3);
            float s0 = n0 < SL1B ? 0.5f * n0 * n0 / SL1B : n0 - 0.5f * SL1B;
            float s1 = n1 < SL1B ? 0.5f * n1 * n1 / SL1B : n1 - 0.5f * SL1B;
            float s2 = n2 < SL1B ? 0.5f * n2 * n2 / SL1B : n2 - 0.5f * SL1B;
            float s3 = n3 < SL1B ? 0.5f * n3 * n3 / SL1B : n3 - 0.5f * SL1B;
            regsum += s0 + s1 + s2 + s3;
            int q = atomicAdd(&npq, 1);
            qpos[q] = ((unsigned)bm << 16) | (unsigned)al;
        }
    }
    __syncthreads();

    // ---------------- phase B1: dense mask-FMA stream (NT loads, batch-5) --------------
    const float4* x4p = (const float4*)logits + ((size_t)bs * NA + a0) * (NC / 4);
    float bgsum = 0.0f;
    #pragma unroll
    for (int g = 0; g < 5; g++) {
        float4 xs[5];
        float  ms[5];
        #pragma unroll
        for (int j = 0; j < 5; j++) {
            int i = t + (g * 5 + j) * 256;
            ms[j] = smask[i / 20];     // LDS, const-divisor magic mul
            xs[j] = ntload4(&x4p[i]);
        }
        #pragma unroll
        for (int j = 0; j < 5; j++) {
            float xv[4] = {xs[j].x, xs[j].y, xs[j].z, xs[j].w};
            float tsum = 0.0f;
            #pragma unroll
            for (int jj = 0; jj < 4; jj++) {
                float x = xv[jj];
                float e = __expf(-x);
                float s = 1.0f + e;
                float pr = __builtin_amdgcn_rcpf(s);
                float ls = __logf(s);
                tsum += (x + ls) * pr;
            }
            bgsum = fmaf(ms[j], tsum, bgsum);
        }
    }

    // ---------------- phase B2: cooperative positive-class corrections -----------------
    // Items = nPos x 20 quads; lanes 0..19 read one row's 320B contiguously (coalesced),
    // all lanes active. corr = w*ls*(e*p) - OMB*(x+ls)*p per y==1 element.
    float corrsum = 0.0f;
    int nq = npq;
    for (int i = t; i < nq * 20; i += 256) {
        int qq = i / 20, c4 = i % 20;
        unsigned e = qpos[qq];
        int al = e & 0xFFFFu;
        int m  = (int)(e >> 16);
        float4 y4 = ((const float4*)(gtl + ((size_t)(bs * NM + m)) * NC))[c4];
        if (y4.x > 0.5f || y4.y > 0.5f || y4.z > 0.5f || y4.w > 0.5f) {
            float4 x4 = ((const float4*)(logits + ((size_t)bs * NA + a0 + al) * NC))[c4];
            float yv[4] = {y4.x, y4.y, y4.z, y4.w};
            float xv[4] = {x4.x, x4.y, x4.z, x4.w};
            #pragma unroll
            for (int j = 0; j < 4; j++) {
                if (yv[j] > 0.5f) {
                    float x = xv[j];
                    float ee = __expf(-x);
                    float s = 1.0f + ee;
                    float pr = __builtin_amdgcn_rcpf(s);
                    float ls = __logf(s);
                    corrsum += ls * wsh[c4 * 4 + j] * (ee * pr)
                             - OMB * (x + ls) * pr;
                }
            }
        }
    }
    float clssum = corrsum + OMB * bgsum;

    // wave shfl-reduce then cross-wave LDS then one atomic per block
    #pragma unroll
    for (int off = 32; off > 0; off >>= 1) {
        regsum += __shfl_xor(regsum, off);
        clssum += __shfl_xor(clssum, off);
        pcnt   += __shfl_xor(pcnt, off);
    }
    __shared__ float sf[4], sc[4];
    __shared__ int   si[4];
    int wave = t >> 6, lane = t & 63;
    if (lane == 0) { sf[wave] = regsum; sc[wave] = clssum; si[wave] = pcnt; }
    __syncthreads();
    if (t == 0) {
        atomicAdd(&acc[0], (double)(sf[0] + sf[1] + sf[2] + sf[3]));
        atomicAdd(&acc[1], (double)(sc[0] + sc[1] + sc[2] + sc[3]));
        atomicAdd(npos, si[0] + si[1] + si[2] + si[3]);
    }
}

// ---------------- kernel 3: ego focal loss + final combine ----------------
__global__ void k_final(const float* __restrict__ ego_preds, const int* __restrict__ ego_labels,
                        const double* __restrict__ acc, const int* __restrict__ npos,
                        float* __restrict__ out) {
    __shared__ float scol[NCE];
    __shared__ float sred[128];
    __shared__ int   sval[128];
    const float EPSF = 1e-7f;
    int t = threadIdx.x;
    if (t < NCE) {
        float c = 0.0f;
        for (int i = 0; i < NBS; i++) {
            int l = ego_labels[i];
            if (l > -1 && l == t) c = 1.0f;
        }
        scol[t] = c;
    }
    __syncthreads();

    float term = 0.0f;
    if (t < NBS * NCE) {
        int bs = t / NCE, e = t % NCE;
        int lbl = ego_labels[bs];
        if (lbl > -1) {
            float x = ego_preds[t];
            float ep = 1.0f / (1.0f + expf(-x));
            float oh = scol[e];
            float af = 0.25f * oh + 0.75f * (1.0f - oh);
            float ept = ep * oh + (1.0f - ep) * (1.0f - oh);
            float epc = fminf(fmaxf(ep, EPSF), 1.0f - EPSF);
            float bce = -(oh * logf(epc) + (1.0f - oh) * log1pf(-epc));
            float om = 1.0f - ept;
            term = bce * af * om * om;
        }
    }
    sred[t] = term;
    sval[t] = (t < NBS && ego_labels[t] > -1) ? 1 : 0;
    __syncthreads();
    for (int off = 64; off > 0; off >>= 1) {
        if (t < off) { sred[t] += sred[t + off]; sval[t] += sval[t + off]; }
        __syncthreads();
    }
    if (t == 0) {
        float esum = sred[0];
        int ne = sval[0];
        float ego = (ne > 0) ? esum / (float)(ne > 1 ? ne : 1) : 0.0f;
        double npd = (double)(*npos);
        if (npd < 1.0) npd = 1.0;
        out[0] = (float)(acc[0] / (npd * 4.0));
        out[1] = (float)(acc[1] / npd / 8.0 + (double)ego / 4.0);
    }
}

// ---------------- host launch ----------------
extern "C" void kernel_launch(void* const* d_in, const int* in_sizes, int n_in,
                              void* d_out, int out_size, void* d_ws, size_t ws_size,
                              hipStream_t stream) {
    const float* confidence = (const float*)d_in[0];
    const float* ploc       = (const float*)d_in[1];
    const float* gtb        = (const float*)d_in[2];
    const float* gtl        = (const float*)d_in[3];
    const int*   counts     = (const int*)d_in[4];
    const float* anchors    = (const float*)d_in[5];
    const float* ego_preds  = (const float*)d_in[6];
    const int*   ego_labels = (const int*)d_in[7];
    const int*   cls_num    = (const int*)d_in[8];
    float* out = (float*)d_out;

    // workspace layout (16B aligned): [acc 2xf64 | npos | pad | gbest 320xu64]
    char* ws = (char*)d_ws;
    double* acc  = (double*)ws;                               // [0]=reg_sum, [1]=cls_sum
    int* npos    = (int*)(ws + 16);
    unsigned long long* gbest = (unsigned long long*)(ws + 64);   // 320 u64 = 2560 B

    hipMemsetAsync(ws, 0, 4096, stream);   // graph memset node: acc, npos, gbest -> 0
    k_gbest<<<NBS * CPB, 256, 0, stream>>>(gtb, counts, anchors, gbest);
    k_match<<<NBS * CPB, 256, 0, stream>>>(gtb, counts, anchors, ploc, gtl, confidence,
                                           cls_num, gbest, acc, npos);
    k_final<<<1, 128, 0, stream>>>(ego_preds, ego_labels, acc, npos, out);
}